// Round 7
// baseline (722.138 us; speedup 1.0000x reference)
//
#include <hip/hip_runtime.h>
#include <math.h>

// Problem constants (match reference setup_inputs()).
#define T_TOK   (64 * 2048)   // N_BATCH * N_ATOMS
#define F_IN    384
#define N1      128
#define N2      96
#define N3      2
#define NEXP    4

#define BM      64            // tokens per block tile
#define KB      32            // K-tile for layer-1 / layer-2 staging
#define XS_LD   (BM + 4)      // padded LDS stride for X^T tile
#define H_LD    (N1 + 4)      // padded LDS stride for H
#define H2_LD   (N2 + 4)      // padded LDS stride for H2

// ws layout (ints): [0..4) counts, [4..8) offsets, [8..12) cursors,
//                   [16 .. 16+T) compacted token list (per-expert segments).
// Total ws requirement: (16 + T) * 4 bytes ~= 525 KB.

// ---------------------------------------------------------------------------
// Pass 1: histogram of elements (wave-aggregated atomics) + passthrough copy
// of elements into d_out as float (tuple output #1, promoted dtype — JAX
// promotion int32+f32 -> f32).
// ---------------------------------------------------------------------------
__global__ __launch_bounds__(256) void hist_kernel(
    const int* __restrict__ el, float* __restrict__ out_el,
    int* __restrict__ counts, int T) {
  int t = blockIdx.x * blockDim.x + threadIdx.x;
  if (t >= T) return;
  int e = el[t];
  out_el[t] = (float)e;
#pragma unroll
  for (int v = 0; v < NEXP; ++v) {
    unsigned long long m = __ballot(e == v);
    if (e == v) {
      int lane = threadIdx.x & 63;
      int leader = __ffsll(m) - 1;
      if (lane == leader) atomicAdd(&counts[v], __popcll(m));
    }
  }
}

// ---------------------------------------------------------------------------
// Pass 2: exclusive scan of 4 counts -> offsets, init scatter cursors.
// ---------------------------------------------------------------------------
__global__ void scan_kernel(int* __restrict__ ws) {
  if (threadIdx.x == 0) {
    int o = 0;
#pragma unroll
    for (int e = 0; e < NEXP; ++e) {
      ws[4 + e] = o;        // offsets
      ws[8 + e] = o;        // cursors
      o += ws[e];           // counts
    }
  }
}

// ---------------------------------------------------------------------------
// Pass 3: scatter token ids into the compacted per-expert segments.
// Wave-aggregated atomics: <=4 atomicAdds per wave. Intra-expert order is
// nondeterministic; MLP result is order-invariant (each token writes its
// own Y row only).
// ---------------------------------------------------------------------------
__global__ __launch_bounds__(256) void scatter_kernel(
    const int* __restrict__ el, int* __restrict__ cursors,
    int* __restrict__ list, int T) {
  int t = blockIdx.x * blockDim.x + threadIdx.x;
  if (t >= T) return;
  int e = el[t];
  int lane = threadIdx.x & 63;
  unsigned long long lt = (lane == 0) ? 0ull : ((~0ull) >> (64 - lane));
#pragma unroll
  for (int v = 0; v < NEXP; ++v) {
    unsigned long long m = __ballot(e == v);
    if (e == v) {
      int leader = __ffsll(m) - 1;
      int prefix = __popcll(m & lt);
      int base = 0;
      if (lane == leader) base = atomicAdd(&cursors[v], __popcll(m));
      base = __shfl(base, leader, 64);
      list[base + prefix] = t;
    }
  }
}

// ---------------------------------------------------------------------------
// Pass 4: fused 3-layer expert MLP over one 64-token tile of one expert.
// grid = (ceil(T/BM), NEXP); blocks past counts[e] early-exit.
// Layer1: h1 = celu(X @ W1 + b1)   [64x384]@[384x128]
// Layer2: h2 = celu(h1 @ W2 + b2)  [64x128]@[128x96]
// Layer3: o  = h2 @ W3 + b3        [64x96]@[96x2], scatter by token id.
// ---------------------------------------------------------------------------
__global__ __launch_bounds__(256) void moe_mlp_kernel(
    const float* __restrict__ X,
    const float* __restrict__ W1, const float* __restrict__ b1,
    const float* __restrict__ W2, const float* __restrict__ b2,
    const float* __restrict__ W3, const float* __restrict__ b3,
    const int* __restrict__ ws_i, float* __restrict__ Y, int T) {
  const int e = blockIdx.y;
  const int cnt = ws_i[e];            // counts[e]
  const int m0 = blockIdx.x * BM;
  if (m0 >= cnt) return;
  const int* list = ws_i + 16 + ws_i[4 + e];   // segment for expert e

  // Single LDS arena, phase-overlapped (barriers separate phases):
  //  A-phase: Xs[KB][XS_LD] @0 ; Ws1[KB][N1] @2176
  //  B-phase: H[BM][H_LD]   @0 ; Ws2[KB][N2] @8448
  //  C-phase: H2[BM][H2_LD] @0 ; W3s[N2*N3]  @6400
  __shared__ float smem[11712];
  __shared__ int toks[BM];
  float* Xs  = smem;
  float* Ws1 = smem + KB * XS_LD;
  float* H   = smem;
  float* Ws2 = smem + BM * H_LD;
  float* H2  = smem;
  float* W3s = smem + BM * H2_LD;

  const int tid = threadIdx.x;     // 256 threads = 16x16
  const int tx = tid & 15;
  const int ty = tid >> 4;

  if (tid < BM) {
    int g = m0 + tid;
    toks[tid] = (g < cnt) ? list[g] : -1;
  }
  __syncthreads();

  // ---------------- Layer 1: acc[4][8] over rows ty*4.., cols tx*8.. --------
  float acc[4][8];
#pragma unroll
  for (int i = 0; i < 4; ++i)
#pragma unroll
    for (int j = 0; j < 8; ++j) acc[i][j] = 0.f;

  const float* W1e = W1 + (size_t)e * F_IN * N1;
  for (int kt = 0; kt < F_IN / KB; ++kt) {
    // Stage X^T tile (gathered rows): Xs[k][m]
    {
      int rr = tid >> 3;              // 0..31
      int kk = (tid & 7) * 4;         // 0..28
#pragma unroll
      for (int p = 0; p < 2; ++p, rr += 32) {
        int tok = toks[rr];
        float4 v = make_float4(0.f, 0.f, 0.f, 0.f);
        if (tok >= 0)
          v = *(const float4*)&X[(size_t)tok * F_IN + kt * KB + kk];
        Xs[(kk + 0) * XS_LD + rr] = v.x;
        Xs[(kk + 1) * XS_LD + rr] = v.y;
        Xs[(kk + 2) * XS_LD + rr] = v.z;
        Xs[(kk + 3) * XS_LD + rr] = v.w;
      }
    }
    // Stage W1 tile [KB][N1] = 4096 floats, 4x float4 per thread.
    {
      const float* src = W1e + kt * KB * N1;
#pragma unroll
      for (int p = 0; p < 4; ++p) {
        int idx = (p * 256 + tid) * 4;
        *(float4*)&Ws1[idx] = *(const float4*)&src[idx];
      }
    }
    __syncthreads();

#pragma unroll
    for (int k = 0; k < KB; ++k) {
      const float4 xv = *(const float4*)&Xs[k * XS_LD + (ty << 2)];
      const float4 wa = *(const float4*)&Ws1[k * N1 + (tx << 3)];
      const float4 wb = *(const float4*)&Ws1[k * N1 + (tx << 3) + 4];
      const float xs[4] = {xv.x, xv.y, xv.z, xv.w};
      const float ws[8] = {wa.x, wa.y, wa.z, wa.w, wb.x, wb.y, wb.z, wb.w};
#pragma unroll
      for (int i = 0; i < 4; ++i)
#pragma unroll
        for (int j = 0; j < 8; ++j)
          acc[i][j] = fmaf(xs[i], ws[j], acc[i][j]);
    }
    __syncthreads();
  }

  // bias + celu, write H[BM][H_LD] (overlaps Xs/Ws1; barrier above done)
  {
    const float* b1e = b1 + e * N1;
    float bv[8];
#pragma unroll
    for (int j = 0; j < 8; ++j) bv[j] = b1e[(tx << 3) + j];
#pragma unroll
    for (int i = 0; i < 4; ++i) {
      float r[8];
#pragma unroll
      for (int j = 0; j < 8; ++j) {
        float v = acc[i][j] + bv[j];
        r[j] = v > 0.f ? v : expm1f(v);
      }
      float* dst = &H[((ty << 2) + i) * H_LD + (tx << 3)];
      *(float4*)dst       = make_float4(r[0], r[1], r[2], r[3]);
      *(float4*)(dst + 4) = make_float4(r[4], r[5], r[6], r[7]);
    }
  }
  __syncthreads();

  // ---------------- Layer 2: acc2[4][6] over rows ty*4.., cols tx*6.. ------
  float acc2[4][6];
#pragma unroll
  for (int i = 0; i < 4; ++i)
#pragma unroll
    for (int j = 0; j < 6; ++j) acc2[i][j] = 0.f;

  const float* W2e = W2 + (size_t)e * N1 * N2;
  for (int kt = 0; kt < N1 / KB; ++kt) {
    {
      const float* src = W2e + kt * KB * N2;   // 3072 floats
#pragma unroll
      for (int p = 0; p < 3; ++p) {
        int idx = (p * 256 + tid) * 4;
        *(float4*)&Ws2[idx] = *(const float4*)&src[idx];
      }
    }
    __syncthreads();

#pragma unroll
    for (int k = 0; k < KB; ++k) {
      float hv[4];
#pragma unroll
      for (int i = 0; i < 4; ++i)
        hv[i] = H[((ty << 2) + i) * H_LD + kt * KB + k];
      const float2 w0 = *(const float2*)&Ws2[k * N2 + tx * 6];
      const float2 w1 = *(const float2*)&Ws2[k * N2 + tx * 6 + 2];
      const float2 w2 = *(const float2*)&Ws2[k * N2 + tx * 6 + 4];
      const float ws[6] = {w0.x, w0.y, w1.x, w1.y, w2.x, w2.y};
#pragma unroll
      for (int i = 0; i < 4; ++i)
#pragma unroll
        for (int j = 0; j < 6; ++j)
          acc2[i][j] = fmaf(hv[i], ws[j], acc2[i][j]);
    }
    __syncthreads();
  }

  // bias + celu, write H2[BM][H2_LD] (overlaps H; all reads done)
  {
    const float* b2e = b2 + e * N2;
    float bv[6];
#pragma unroll
    for (int j = 0; j < 6; ++j) bv[j] = b2e[tx * 6 + j];
#pragma unroll
    for (int i = 0; i < 4; ++i) {
      float r[6];
#pragma unroll
      for (int j = 0; j < 6; ++j) {
        float v = acc2[i][j] + bv[j];
        r[j] = v > 0.f ? v : expm1f(v);
      }
      float* dst = &H2[((ty << 2) + i) * H2_LD + tx * 6];
      *(float2*)dst       = make_float2(r[0], r[1]);
      *(float2*)(dst + 2) = make_float2(r[2], r[3]);
      *(float2*)(dst + 4) = make_float2(r[4], r[5]);
    }
  }
  if (tid < N2 * N3) W3s[tid] = W3[e * N2 * N3 + tid];
  __syncthreads();

  // ---------------- Layer 3: 128 threads, one (token, out-channel) each ----
  if (tid < BM * N3) {
    const int m = tid >> 1;
    const int c = tid & 1;
    float s = b3[e * N3 + c];
#pragma unroll
    for (int k4 = 0; k4 < N2; k4 += 4) {
      const float4 h = *(const float4*)&H2[m * H2_LD + k4];
      s = fmaf(h.x, W3s[(k4 + 0) * N3 + c], s);
      s = fmaf(h.y, W3s[(k4 + 1) * N3 + c], s);
      s = fmaf(h.z, W3s[(k4 + 2) * N3 + c], s);
      s = fmaf(h.w, W3s[(k4 + 3) * N3 + c], s);
    }
    const int tok = toks[m];
    if (tok >= 0) Y[(size_t)tok * N3 + c] = s;
  }
}

// ---------------------------------------------------------------------------
extern "C" void kernel_launch(void* const* d_in, const int* in_sizes, int n_in,
                              void* d_out, int out_size, void* d_ws, size_t ws_size,
                              hipStream_t stream) {
  const int*   elements = (const int*)d_in[0];
  const float* X  = (const float*)d_in[1];
  const float* W1 = (const float*)d_in[2];
  const float* b1 = (const float*)d_in[3];
  const float* W2 = (const float*)d_in[4];
  const float* b2 = (const float*)d_in[5];
  const float* W3 = (const float*)d_in[6];
  const float* b3 = (const float*)d_in[7];
  const int T = in_sizes[0];        // 131072 tokens

  float* out    = (float*)d_out;
  float* out_el = out;              // output #1: elements (promoted to float)
  float* Y      = out + T;          // output #2: y [T, 2]

  int* ws_i    = (int*)d_ws;
  int* counts  = ws_i;              // [0..4)
  int* cursors = ws_i + 8;          // [8..12)
  int* list    = ws_i + 16;         // T ints

  hipMemsetAsync(ws_i, 0, 16 * sizeof(int), stream);
  int nb = (T + 255) / 256;
  hist_kernel<<<nb, 256, 0, stream>>>(elements, out_el, counts, T);
  scan_kernel<<<1, 64, 0, stream>>>(ws_i);
  scatter_kernel<<<nb, 256, 0, stream>>>(elements, cursors, list, T);
  dim3 grid((T + BM - 1) / BM, NEXP);
  moe_mlp_kernel<<<grid, 256, 0, stream>>>(X, W1, b1, W2, b2, W3, b3,
                                           ws_i, Y, T);
}

// Round 8
// 532.679 us; speedup vs baseline: 1.3557x; 1.3557x over previous
//
#include <hip/hip_runtime.h>
#include <math.h>

// Problem constants (match reference setup_inputs()).
#define F_IN    384
#define N1      128
#define N2      96
#define N3      2
#define NEXP    4
#define BM      64            // tokens per block tile

typedef __attribute__((ext_vector_type(8))) short           bf16x8;   // MFMA A/B frag
typedef __attribute__((ext_vector_type(4))) float           f32x4;    // MFMA C/D frag
typedef __attribute__((ext_vector_type(4))) unsigned short  us4;
typedef __attribute__((ext_vector_type(8))) unsigned short  us8;

// fp32 -> bf16 RNE (values are finite; no NaN handling needed)
__device__ __forceinline__ unsigned short f2bf(float f) {
  unsigned int u = __float_as_uint(f);
  return (unsigned short)((u + 0x7FFFu + ((u >> 16) & 1u)) >> 16);
}

// ws layout:
//   ints [0..4) counts, [4..8) offsets, [8..12) cursors, [16..16+T) token list
//   byte 64+4T (64B-aligned): Wt1 [4][128][384] bf16 (393216 B)
//   then:                     Wt2 [4][96][128]  bf16 ( 98304 B)
// Total ws requirement ~1.02 MB.

// ---------------------------------------------------------------------------
// Pass 1: histogram + elements passthrough (as float — confirmed PASS r7).
// ---------------------------------------------------------------------------
__global__ __launch_bounds__(256) void hist_kernel(
    const int* __restrict__ el, float* __restrict__ out_el,
    int* __restrict__ counts, int T) {
  int t = blockIdx.x * blockDim.x + threadIdx.x;
  if (t >= T) return;
  int e = el[t];
  out_el[t] = (float)e;
#pragma unroll
  for (int v = 0; v < NEXP; ++v) {
    unsigned long long m = __ballot(e == v);
    if (e == v) {
      int lane = threadIdx.x & 63;
      int leader = __ffsll(m) - 1;
      if (lane == leader) atomicAdd(&counts[v], __popcll(m));
    }
  }
}

__global__ void scan_kernel(int* __restrict__ ws) {
  if (threadIdx.x == 0) {
    int o = 0;
#pragma unroll
    for (int e = 0; e < NEXP; ++e) {
      ws[4 + e] = o;
      ws[8 + e] = o;
      o += ws[e];
    }
  }
}

__global__ __launch_bounds__(256) void scatter_kernel(
    const int* __restrict__ el, int* __restrict__ cursors,
    int* __restrict__ list, int T) {
  int t = blockIdx.x * blockDim.x + threadIdx.x;
  if (t >= T) return;
  int e = el[t];
  int lane = threadIdx.x & 63;
  unsigned long long lt = (lane == 0) ? 0ull : ((~0ull) >> (64 - lane));
#pragma unroll
  for (int v = 0; v < NEXP; ++v) {
    unsigned long long m = __ballot(e == v);
    if (e == v) {
      int leader = __ffsll(m) - 1;
      int prefix = __popcll(m & lt);
      int base = 0;
      if (lane == leader) base = atomicAdd(&cursors[v], __popcll(m));
      base = __shfl(base, leader, 64);
      list[base + prefix] = t;
    }
  }
}

// ---------------------------------------------------------------------------
// Weight prep: W1 [e][k][n] f32 -> Wt1 [e][n][k] bf16;  W2 likewise.
// Runs every launch (ws is re-poisoned). ~246K elems; output coalesced.
// ---------------------------------------------------------------------------
__global__ __launch_bounds__(256) void prep_weights(
    const float* __restrict__ W1, const float* __restrict__ W2,
    unsigned short* __restrict__ Wt1, unsigned short* __restrict__ Wt2) {
  int i = blockIdx.x * 256 + threadIdx.x;
  const int n1 = NEXP * N1 * F_IN;           // 196608
  if (i < n1) {
    int e = i / (N1 * F_IN), r = i % (N1 * F_IN);
    int n = r / F_IN, k = r % F_IN;
    Wt1[i] = f2bf(W1[(e * F_IN + k) * N1 + n]);
  } else {
    int j = i - n1;
    if (j < NEXP * N2 * N1) {
      int e = j / (N2 * N1), r = j % (N2 * N1);
      int n = r / N1, k = r % N1;
      Wt2[j] = f2bf(W2[(e * N1 + k) * N2 + n]);
    }
  }
}

// ---------------------------------------------------------------------------
// Fused 3-layer MLP, bf16 MFMA for L1+L2, fp32 VALU L3.
// 256 thr = 4 waves. Fragment conventions (mfma_f32_16x16x32_bf16):
//   A[m][k]: m=lane&15, k=(lane>>4)*8+j   B[k][n]: n=lane&15, k=(lane>>4)*8+j
//   C/D[r][c]: c=lane&15, r=(lane>>4)*4+reg   [guide §3, m89-verified]
// LDS arena (ushort units), phase-overlapped:
//   Xs  @0     [64][40]     (5120 B)   | L1, padded stride: conflict-free b128
//   Ws1 @2560  [128][40]    (10240 B)  | L1
//   H   @0     [64][136]    (17408 B)  | L1 out / L2 A (overlaps Xs+Ws1)
//   Ws2 @8704  [96][40]     (7680 B)   | L2 B chunk
//   H2  @0     [64][100] f32 (25600 B) | L2 out / L3 in (overlaps H+Ws2)
//   W3s @12800 192 f32       (768 B)
// ---------------------------------------------------------------------------
__global__ __launch_bounds__(256) void moe_mlp_mfma(
    const float* __restrict__ X,
    const float* __restrict__ b1, const float* __restrict__ b2,
    const float* __restrict__ W3, const float* __restrict__ b3,
    const int* __restrict__ ws_i,
    const unsigned short* __restrict__ Wt1,
    const unsigned short* __restrict__ Wt2,
    float* __restrict__ Y, int T) {
  const int e = blockIdx.y;
  const int cnt = ws_i[e];
  const int m0 = blockIdx.x * BM;
  if (m0 >= cnt) return;
  const int* list = ws_i + 16 + ws_i[4 + e];

  __shared__ __align__(16) unsigned short arena[13184];
  __shared__ int toks[BM];
  unsigned short* XsU  = arena;
  unsigned short* Ws1U = arena + 2560;
  unsigned short* HU   = arena;
  unsigned short* Ws2U = arena + 8704;
  float* H2f = (float*)arena;
  float* W3s = (float*)(arena + 12800);

  const int tid  = threadIdx.x;
  const int lane = tid & 63;
  const int w    = tid >> 6;      // wave 0..3
  const int ln15 = lane & 15;
  const int g    = lane >> 4;     // 0..3

  if (tid < BM) {
    int gi = m0 + tid;
    toks[tid] = (gi < cnt) ? list[gi] : -1;
  }
  __syncthreads();

  // ---------------- Layer 1: [64x384]@[384x128], 2x2 wave grid -------------
  const int wr = w >> 1, wc = w & 1;   // wave rows wr*32.., cols wc*64..
  f32x4 acc[2][4];
#pragma unroll
  for (int i = 0; i < 2; ++i)
#pragma unroll
    for (int j = 0; j < 4; ++j) acc[i][j] = (f32x4){0.f, 0.f, 0.f, 0.f};

  const unsigned short* Wt1e = Wt1 + (size_t)e * (N1 * F_IN);
  for (int ks = 0; ks < F_IN / 32; ++ks) {
    const int k0 = ks * 32;
    // Stage Xs[m][k] bf16 (gathered rows, convert in-flight)
#pragma unroll
    for (int p = 0; p < 2; ++p) {
      int q = p * 256 + tid;
      int m = q >> 3, kq = (q & 7) * 4;
      int tok = toks[m];
      float4 v = make_float4(0.f, 0.f, 0.f, 0.f);
      if (tok >= 0) v = *(const float4*)&X[(size_t)tok * F_IN + k0 + kq];
      us4 b4; b4.x = f2bf(v.x); b4.y = f2bf(v.y); b4.z = f2bf(v.z); b4.w = f2bf(v.w);
      *(us4*)&XsU[m * 40 + kq] = b4;
    }
    // Stage Ws1[n][k] bf16 (pre-transposed global -> pure 16B copies)
#pragma unroll
    for (int p = 0; p < 2; ++p) {
      int q = p * 256 + tid;
      int n = q >> 2, h = q & 3;
      *(us8*)&Ws1U[n * 40 + h * 8] = *(const us8*)&Wt1e[n * F_IN + k0 + h * 8];
    }
    __syncthreads();

    bf16x8 af[2], bf[4];
#pragma unroll
    for (int rt = 0; rt < 2; ++rt)
      af[rt] = *(const bf16x8*)&XsU[(wr * 32 + rt * 16 + ln15) * 40 + g * 8];
#pragma unroll
    for (int ct = 0; ct < 4; ++ct)
      bf[ct] = *(const bf16x8*)&Ws1U[(wc * 64 + ct * 16 + ln15) * 40 + g * 8];
#pragma unroll
    for (int rt = 0; rt < 2; ++rt)
#pragma unroll
      for (int ct = 0; ct < 4; ++ct)
        acc[rt][ct] = __builtin_amdgcn_mfma_f32_16x16x32_bf16(
            af[rt], bf[ct], acc[rt][ct], 0, 0, 0);
    __syncthreads();
  }

  // bias + celu (f32), write H bf16 (overlaps Xs/Ws1; loop ended on barrier)
#pragma unroll
  for (int rt = 0; rt < 2; ++rt)
#pragma unroll
    for (int ct = 0; ct < 4; ++ct) {
      int c = wc * 64 + ct * 16 + ln15;
      float bias = b1[e * N1 + c];
#pragma unroll
      for (int r = 0; r < 4; ++r) {
        float v = acc[rt][ct][r] + bias;
        v = v > 0.f ? v : expm1f(v);
        HU[(wr * 32 + rt * 16 + g * 4 + r) * 136 + c] = f2bf(v);
      }
    }
  __syncthreads();

  // ---------------- Layer 2: [64x128]@[128x96], wave w owns rows w*16 ------
  f32x4 acc2[6];
#pragma unroll
  for (int j = 0; j < 6; ++j) acc2[j] = (f32x4){0.f, 0.f, 0.f, 0.f};

  const unsigned short* Wt2e = Wt2 + (size_t)e * (N2 * N1);
  for (int ks = 0; ks < N1 / 32; ++ks) {
    const int k0 = ks * 32;
#pragma unroll
    for (int p = 0; p < 2; ++p) {
      int q = p * 256 + tid;
      if (q < 384) {
        int n = q >> 2, h = q & 3;
        *(us8*)&Ws2U[n * 40 + h * 8] = *(const us8*)&Wt2e[n * N1 + k0 + h * 8];
      }
    }
    __syncthreads();

    bf16x8 a = *(const bf16x8*)&HU[(w * 16 + ln15) * 136 + k0 + g * 8];
#pragma unroll
    for (int ct = 0; ct < 6; ++ct) {
      bf16x8 b = *(const bf16x8*)&Ws2U[(ct * 16 + ln15) * 40 + g * 8];
      acc2[ct] = __builtin_amdgcn_mfma_f32_16x16x32_bf16(a, b, acc2[ct], 0, 0, 0);
    }
    __syncthreads();
  }

  // bias + celu (f32), write H2 f32 (overlaps H/Ws2; all L2 reads done)
#pragma unroll
  for (int ct = 0; ct < 6; ++ct) {
    int c = ct * 16 + ln15;
    float bias = b2[e * N2 + c];
#pragma unroll
    for (int r = 0; r < 4; ++r) {
      float v = acc2[ct][r] + bias;
      v = v > 0.f ? v : expm1f(v);
      H2f[(w * 16 + g * 4 + r) * 100 + c] = v;
    }
  }
  if (tid < N2 * N3) W3s[tid] = W3[e * N2 * N3 + tid];
  __syncthreads();

  // ---------------- Layer 3: [64x96]@[96x2], fp32 VALU ---------------------
  if (tid < BM * N3) {
    const int m = tid >> 1;
    const int c = tid & 1;
    float s = b3[e * N3 + c];
#pragma unroll
    for (int k4 = 0; k4 < N2; k4 += 4) {
      const float4 h = *(const float4*)&H2f[m * 100 + k4];
      s = fmaf(h.x, W3s[(k4 + 0) * N3 + c], s);
      s = fmaf(h.y, W3s[(k4 + 1) * N3 + c], s);
      s = fmaf(h.z, W3s[(k4 + 2) * N3 + c], s);
      s = fmaf(h.w, W3s[(k4 + 3) * N3 + c], s);
    }
    const int tok = toks[m];
    if (tok >= 0) Y[(size_t)tok * N3 + c] = s;
  }
}

// ---------------------------------------------------------------------------
extern "C" void kernel_launch(void* const* d_in, const int* in_sizes, int n_in,
                              void* d_out, int out_size, void* d_ws, size_t ws_size,
                              hipStream_t stream) {
  const int*   elements = (const int*)d_in[0];
  const float* X  = (const float*)d_in[1];
  const float* W1 = (const float*)d_in[2];
  const float* b1 = (const float*)d_in[3];
  const float* W2 = (const float*)d_in[4];
  const float* b2 = (const float*)d_in[5];
  const float* W3 = (const float*)d_in[6];
  const float* b3 = (const float*)d_in[7];
  const int T = in_sizes[0];        // 131072 tokens

  float* out    = (float*)d_out;
  float* out_el = out;              // output #1: elements (promoted to float)
  float* Y      = out + T;          // output #2: y [T, 2]

  int* ws_i    = (int*)d_ws;
  int* counts  = ws_i;              // [0..4)
  int* cursors = ws_i + 8;          // [8..12)
  int* list    = ws_i + 16;         // T ints

  size_t wt1_off = ((size_t)64 + 4 * (size_t)T + 63) & ~(size_t)63;
  unsigned short* Wt1 = (unsigned short*)((char*)d_ws + wt1_off);
  unsigned short* Wt2 = Wt1 + NEXP * N1 * F_IN;     // +393216 B

  hipMemsetAsync(ws_i, 0, 16 * sizeof(int), stream);
  int nb = (T + 255) / 256;
  hist_kernel<<<nb, 256, 0, stream>>>(elements, out_el, counts, T);
  scan_kernel<<<1, 64, 0, stream>>>(ws_i);
  scatter_kernel<<<nb, 256, 0, stream>>>(elements, cursors, list, T);
  prep_weights<<<(NEXP * N1 * F_IN + NEXP * N2 * N1 + 255) / 256, 256, 0, stream>>>(
      W1, W2, Wt1, Wt2);
  dim3 grid((T + BM - 1) / BM, NEXP);
  moe_mlp_mfma<<<grid, 256, 0, stream>>>(X, b1, b2, W3, b3, ws_i, Wt1, Wt2, Y, T);
}